// Round 18
// baseline (12028.673 us; speedup 1.0000x reference)
//
#include <hip/hip_runtime.h>
#include <hip/hip_bf16.h>

// Problem constants
#define SEQ  256
#define BSZ  128
#define DM   512
#define HID  1536
#define KTOT 2560      // x(512) | r(512) | h(1536)
#define VC   6144      // virtual cols: [0,3072) fused rz, [3072,4608) inn, [4608,6144) hn
#define NBLK 720       // persistent grid = 45 groups x 16

typedef __attribute__((ext_vector_type(4))) float f32x4;
typedef __attribute__((ext_vector_type(8))) short short8;
typedef __attribute__((ext_vector_type(4))) unsigned short us4;
typedef __attribute__((ext_vector_type(8))) unsigned short us8;
typedef __attribute__((ext_vector_type(4))) unsigned int u32x4;

// ws layout (bytes)
#define OFF_WBH 0ull                 // bf16 [4608][2560]      = 23,592,960
#define OFF_P   47185920ull          // f32  [5][128][6144]    = 15,728,640
#define OFF_R32 62914560ull          // f32  [128][512]  (written only at t=255)
#define OFF_RBH 80740352ull          // bf16 [128][512]        (zeroed)
#define OFF_HBH 81002496ull          // bf16 [128][1536]       (zeroed)
#define OFF_BAR 81788928ull          // 1024 uints: root@0, ep@32, gcnt[g]@64+g*16, xcdcnt@832+x*16
// pk_zero region: OFF_RBH..OFF_BAR = 1,048,576 B = 65,536 x 16B = 256 blocks x 256

static __device__ __forceinline__ unsigned short bf(float x) {
  __hip_bfloat16 h = __float2bfloat16(x);
  return *reinterpret_cast<unsigned short*>(&h);
}

// ---- coherence policy: per-XCD L2 for W (plain loads); acts/x sc0|sc1 (LLC-direct);
// P/Hb/Rb sc0|sc1 write-through.
static __device__ __forceinline__ void stf_llc(float* p, float v) {
  asm volatile("global_store_dword %0, %1, off sc0 sc1" :: "v"(p), "v"(v) : "memory");
}
static __device__ __forceinline__ void st16_llc(unsigned short* p, unsigned short v) {
  unsigned vv = v;
  asm volatile("global_store_short %0, %1, off sc0 sc1" :: "v"(p), "v"(vv) : "memory");
}
static __device__ __forceinline__ float ldf_llc(const float* p) {
  return __hip_atomic_load(p, __ATOMIC_RELAXED, __HIP_MEMORY_SCOPE_SYSTEM);
}
static __device__ __forceinline__ unsigned sysld(unsigned* p) {
  return __hip_atomic_load(p, __ATOMIC_RELAXED, __HIP_MEMORY_SCOPE_SYSTEM);
}

// ---- async issue: wave-local, NO embedded waits (counted vmcnt in the loop) ----
// acts path: 1 acts (sc0|sc1) + 4 W (plain). (j)*32 shorts = 64B k-advance.
#define ISS_B(a_, w0_, w1_, w2_, w3_, j)                                   \
  asm volatile("global_load_dwordx4 %0, %5, off sc0 sc1\n\t"              \
               "global_load_dwordx4 %1, %6, off\n\t"                       \
               "global_load_dwordx4 %2, %7, off\n\t"                       \
               "global_load_dwordx4 %3, %8, off\n\t"                       \
               "global_load_dwordx4 %4, %9, off"                           \
               : "=&v"(a_), "=&v"(w0_), "=&v"(w1_), "=&v"(w2_), "=&v"(w3_) \
               : "v"(actbase + (j) * 32), "v"(wb0 + (j) * 32),             \
                 "v"(wb1 + (j) * 32), "v"(wb2 + (j) * 32),                 \
                 "v"(wb3 + (j) * 32)                                       \
               : "memory");
// x path: 2 f32 dwordx4 (sc0|sc1) + 4 W. (j)*32 floats = 128B k-advance.
#define ISS_X(f0_, f1_, w0_, w1_, w2_, w3_, j)                             \
  asm volatile("global_load_dwordx4 %0, %6, off sc0 sc1\n\t"              \
               "global_load_dwordx4 %1, %7, off sc0 sc1\n\t"              \
               "global_load_dwordx4 %2, %8, off\n\t"                       \
               "global_load_dwordx4 %3, %9, off\n\t"                       \
               "global_load_dwordx4 %4, %10, off\n\t"                      \
               "global_load_dwordx4 %5, %11, off"                          \
               : "=&v"(f0_), "=&v"(f1_), "=&v"(w0_), "=&v"(w1_),           \
                 "=&v"(w2_), "=&v"(w3_)                                    \
               : "v"(xbase + (j) * 32), "v"(xbase + (j) * 32 + 4),         \
                 "v"(wb0 + (j) * 32), "v"(wb1 + (j) * 32),                 \
                 "v"(wb2 + (j) * 32), "v"(wb3 + (j) * 32)                  \
               : "memory");

#define WAITV(N)                                                           \
  asm volatile("s_waitcnt vmcnt(" #N ")" ::: "memory");                    \
  __builtin_amdgcn_sched_barrier(0);

// ---- grid barrier: hierarchical RMW arrive at LLC + SYSTEM poll. NO cache fences.
static __device__ __forceinline__ void gsync(unsigned* bar) {
  asm volatile("s_waitcnt vmcnt(0)" ::: "memory");
  __syncthreads();
  if (threadIdx.x == 0) {
    unsigned* root = bar;
    unsigned* ep   = bar + 32;
    unsigned* gcnt = bar + 64 + (blockIdx.x >> 4) * 16;   // 45 groups x 16
    unsigned e = sysld(ep);
    if (atomicAdd(gcnt, 1u) == 15u) {
      atomicSub(gcnt, 16u);
      if (atomicAdd(root, 1u) == 44u) {
        atomicSub(root, 45u);
        atomicAdd(ep, 1u);
      }
    }
    while (sysld(ep) == e) __builtin_amdgcn_s_sleep(8);
  }
  __syncthreads();
}

// ---------------- prep: repack weights to bf16 [4608][2560]; zero barrier ----------------
__global__ __launch_bounds__(256) void pk_wb(const float* __restrict__ Wih,
                                             const float* __restrict__ Whh,
                                             unsigned short* __restrict__ Wh,
                                             unsigned* __restrict__ bar) {
  if (blockIdx.x == 0)
    for (int i = threadIdx.x; i < 1024; i += 256) bar[i] = 0u;
  int idx = blockIdx.x * 256 + threadIdx.x;        // < 4608*640 = 2,949,120
  int row = idx / 640;
  int k = (idx - row * 640) * 4;
  const float* src = (k < 1024) ? (Wih + (size_t)row * 1024 + k)
                                : (Whh + (size_t)row * HID + (k - 1024));
  f32x4 v = *(const f32x4*)src;
  us4 oh;
#pragma unroll
  for (int i = 0; i < 4; ++i) oh[i] = bf(v[i]);
  *(us4*)(Wh + (size_t)row * KTOT + k) = oh;
}

__global__ __launch_bounds__(256) void pk_zero(f32x4* __restrict__ dst) {
  f32x4 z = {0.f, 0.f, 0.f, 0.f};
  dst[(size_t)blockIdx.x * 256 + threadIdx.x] = z;
}

// ---------------- persistent fused kernel: 256 x (GEMM | pair) ----------------
// 720 blocks x 256 threads, 3/CU. 720 tasks = 8 XCD x 90, tile [64b x 64c x 512k].
// NEW: wave = 16 batches x 64 cols; acts staged in a PRIVATE per-wave LDS buffer
// (same-wave write/read -> lgkmcnt only, ZERO s_barriers in the GEMM phase).
// Waves free-run -> full memory concurrency for the W stream.
__global__ __launch_bounds__(256, 3) void fused(
    const float* __restrict__ x, const float* __restrict__ bih,
    const float* __restrict__ bhh, char* __restrict__ ws,
    float* __restrict__ dout)
{
  const unsigned short* Wh = (const unsigned short*)(ws + OFF_WBH);
  float*          P   = (float*)(ws + OFF_P);
  float*          r32 = (float*)(ws + OFF_R32);
  unsigned short* Rbh = (unsigned short*)(ws + OFF_RBH);
  unsigned short* Hbh = (unsigned short*)(ws + OFF_HBH);
  unsigned* bar = (unsigned*)(ws + OFF_BAR);

  const int blk = blockIdx.x;
  const int tid = threadIdx.x;

  // ---- XCD rendezvous: fixed rank within this physical XCD ----
  unsigned xcd;
  asm volatile("s_getreg_b32 %0, hwreg(HW_REG_XCC_ID)" : "=s"(xcd));
  xcd &= 7;
  __shared__ unsigned rankS;
  if (tid == 0) rankS = atomicAdd(&bar[832 + xcd * 16], 1u);
  __syncthreads();
  const unsigned rank = rankS;

  const int wave = tid >> 6, lane = tid & 63;
  const int l15 = lane & 15, kg = lane >> 4;
  const int bw16 = wave * 16;             // wave's 16-batch slice of the 64-batch tile
  const int srow = lane >> 2;             // staging row 0..15 (this wave's batches)
  const int scol = (lane & 3) * 8;        // staging col (8 shorts)

  __shared__ __align__(16) unsigned short SB[4][2][16 * 36];  // per-wave dbuf staging
  __shared__ __align__(16) float Alds[2][64 * 65];            // per-pair fast weights
  __shared__ float kS[2][64];
  __shared__ float qS[2][64];

  // ---- init: zero A (LDS) ----
  for (int i = tid; i < 2 * 64 * 65; i += 256) ((float*)Alds)[i] = 0.f;
  float hprev[3] = {0.f, 0.f, 0.f};       // per-pair-lane GRU state (waves 0,1 of blk<512)
  gsync(bar);                             // also: all ranks registered
  const unsigned cnt_g = sysld(&bar[832 + xcd * 16]);

  for (int t = 0; t < SEQ; ++t) {
    // ===== GEMM phase: this XCD's 90 tasks, strided over its blocks =====
    for (unsigned v = rank; v < 90u; v += cnt_g) {
      int jg, ks, half;
      if (v < 60u)      { jg = 6 * xcd + v / 10;                unsigned r = v % 10; ks = r >> 1; half = r & 1; }
      else if (v < 72u) { unsigned w = v - 60; jg = 48 + 3 * xcd + w / 4; unsigned r = w % 4; ks = r >> 1;       half = r & 1; }
      else              { unsigned w = v - 72; jg = 72 + 3 * xcd + w / 6; unsigned r = w % 6; ks = 2 + (r >> 1); half = r & 1; }
      int colb, wrowb;
      if (jg < 48)      { colb = jg * 64;               wrowb = colb; }          // rz
      else if (jg < 72) { colb = 3072 + (jg - 48) * 64; wrowb = colb; }          // inn
      else              { colb = 4608 + (jg - 72) * 64; wrowb = colb - 1536; }   // hn
      const int kc0 = ks * 512;
      const int b0g = half * 64;

      const unsigned short* wb0 = Wh + (size_t)(wrowb + l15) * KTOT + kc0 + kg * 8;
      const unsigned short* wb1 = wb0 + (size_t)16 * KTOT;
      const unsigned short* wb2 = wb0 + (size_t)32 * KTOT;
      const unsigned short* wb3 = wb0 + (size_t)48 * KTOT;
      unsigned short* sb0 = &SB[wave][0][0];
      unsigned short* sb1 = &SB[wave][1][0];

      f32x4 acc0 = {0.f,0.f,0.f,0.f}, acc1 = {0.f,0.f,0.f,0.f};
      f32x4 acc2 = {0.f,0.f,0.f,0.f}, acc3 = {0.f,0.f,0.f,0.f};

      asm volatile("s_waitcnt vmcnt(0)" ::: "memory");   // drain prev task's P stores

      if (ks == 0) {
        // ---- x path: f32 -> bf16, depth-2, 6 loads/slot, wave-local ----
        const float* xbase = x + ((size_t)(t * BSZ + b0g + bw16 + srow)) * DM + kc0 + scol;
        u32x4 fA0, fA1, wA0, wA1, wA2, wA3, fB0, fB1, wB0, wB1, wB2, wB3;
        ISS_X(fA0, fA1, wA0, wA1, wA2, wA3, 0);
        ISS_X(fB0, fB1, wB0, wB1, wB2, wB3, 1);
#pragma unroll
        for (int it = 0; it < 16; ++it) {
          if (it < 15) { WAITV(6) } else { WAITV(0) }
          const int sl = it & 1;
          f32x4 f0 = sl ? *(f32x4*)&fB0 : *(f32x4*)&fA0;
          f32x4 f1 = sl ? *(f32x4*)&fB1 : *(f32x4*)&fA1;
          us8 h0;
#pragma unroll
          for (int i = 0; i < 4; ++i) {
            h0[i]     = bf(f0[i]);
            h0[4 + i] = bf(f1[i]);
          }
          unsigned short* sb = sl ? sb1 : sb0;
          *(us8*)&sb[srow * 36 + scol] = h0;                       // wave-local write
          short8 ah = *(const short8*)&sb[l15 * 36 + kg * 8];      // wave-local read
          short8 w0 = sl ? *(short8*)&wB0 : *(short8*)&wA0;
          short8 w1 = sl ? *(short8*)&wB1 : *(short8*)&wA1;
          short8 w2 = sl ? *(short8*)&wB2 : *(short8*)&wA2;
          short8 w3 = sl ? *(short8*)&wB3 : *(short8*)&wA3;
          acc0 = __builtin_amdgcn_mfma_f32_16x16x32_bf16(ah, w0, acc0, 0, 0, 0);
          acc1 = __builtin_amdgcn_mfma_f32_16x16x32_bf16(ah, w1, acc1, 0, 0, 0);
          acc2 = __builtin_amdgcn_mfma_f32_16x16x32_bf16(ah, w2, acc2, 0, 0, 0);
          acc3 = __builtin_amdgcn_mfma_f32_16x16x32_bf16(ah, w3, acc3, 0, 0, 0);
          if (it < 14) {
            if (sl) { ISS_X(fB0, fB1, wB0, wB1, wB2, wB3, it + 2) }
            else    { ISS_X(fA0, fA1, wA0, wA1, wA2, wA3, it + 2) }
          }
        }
      } else {
        // ---- bf16 acts path (r or h), depth-2, 5 loads/slot, wave-local ----
        const unsigned short* actbase =
            (ks == 1) ? (Rbh + (size_t)(b0g + bw16 + srow) * DM + (kc0 - 512) + scol)
                      : (Hbh + (size_t)(b0g + bw16 + srow) * HID + (kc0 - 1024) + scol);
        u32x4 aA, wA0, wA1, wA2, wA3, aB, wB0, wB1, wB2, wB3;
        ISS_B(aA, wA0, wA1, wA2, wA3, 0);
        ISS_B(aB, wB0, wB1, wB2, wB3, 1);
#pragma unroll
        for (int it = 0; it < 16; ++it) {
          if (it < 15) { WAITV(5) } else { WAITV(0) }
          const int sl = it & 1;
          u32x4 av = sl ? aB : aA;
          unsigned short* sb = sl ? sb1 : sb0;
          *(u32x4*)&sb[srow * 36 + scol] = av;                     // wave-local write
          short8 ah = *(const short8*)&sb[l15 * 36 + kg * 8];      // wave-local read
          short8 w0 = sl ? *(short8*)&wB0 : *(short8*)&wA0;
          short8 w1 = sl ? *(short8*)&wB1 : *(short8*)&wA1;
          short8 w2 = sl ? *(short8*)&wB2 : *(short8*)&wA2;
          short8 w3 = sl ? *(short8*)&wB3 : *(short8*)&wA3;
          acc0 = __builtin_amdgcn_mfma_f32_16x16x32_bf16(ah, w0, acc0, 0, 0, 0);
          acc1 = __builtin_amdgcn_mfma_f32_16x16x32_bf16(ah, w1, acc1, 0, 0, 0);
          acc2 = __builtin_amdgcn_mfma_f32_16x16x32_bf16(ah, w2, acc2, 0, 0, 0);
          acc3 = __builtin_amdgcn_mfma_f32_16x16x32_bf16(ah, w3, acc3, 0, 0, 0);
          if (it < 14) {
            if (sl) { ISS_B(aB, wB0, wB1, wB2, wB3, it + 2) }
            else    { ISS_B(aA, wA0, wA1, wA2, wA3, it + 2) }
          }
        }
      }

      // P partials: write THROUGH to LLC (cross-XCD consumers)
      float* Pw = P + ((size_t)ks * BSZ + b0g + bw16 + kg * 4) * VC + colb + l15;
#pragma unroll
      for (int i = 0; i < 4; ++i) {
        stf_llc(Pw + (size_t)i * VC,      acc0[i]);
        stf_llc(Pw + (size_t)i * VC + 16, acc1[i]);
        stf_llc(Pw + (size_t)i * VC + 32, acc2[i]);
        stf_llc(Pw + (size_t)i * VC + 48, acc3[i]);
      }
    }
    gsync(bar);

    // ================= pair phase (blocks 0..511, waves 0..1, 1 pair each) ==========
    if (blk < 512 && wave < 2) {
      const int pair = blk * 2 + wave;
      const int b = pair >> 3, n = pair & 7;
      const int l = lane;
      const float* Pb = P + (size_t)b * VC;
      float hv[3];
#pragma unroll
      for (int s = 0; s < 3; ++s) {
        int c = s * 512 + n * 64 + l;
        float sr2 = 0.f, sz = 0.f;
#pragma unroll
        for (int ksi = 0; ksi < 5; ++ksi) {
          const float* q = Pb + (size_t)ksi * BSZ * VC;
          sr2 += ldf_llc(q + c);
          sz  += ldf_llc(q + 1536 + c);
        }
        float gin = ldf_llc(Pb + 3072 + c) + ldf_llc(Pb + (size_t)BSZ * VC + 3072 + c);
        float ghn = 0.f;
#pragma unroll
        for (int ksi = 2; ksi < 5; ++ksi)
          ghn += ldf_llc(Pb + (size_t)ksi * BSZ * VC + 4608 + c);
        float rg = 1.f / (1.f + __expf(-(sr2 + bih[c] + bhh[c])));
        float zg = 1.f / (1.f + __expf(-(sz + bih[1536 + c] + bhh[1536 + c])));
        float nn = tanhf(gin + bih[3072 + c] + rg * (ghn + bhh[3072 + c]));
        float hnew = (1.f - zg) * nn + zg * hprev[s];
        hprev[s] = hnew;
        size_t hix = (size_t)b * HID + c;
        st16_llc(&Hbh[hix], bf(hnew));
        hv[s] = hnew;
      }
      float ssq = hv[0] * hv[0], ssk = hv[1] * hv[1];
#pragma unroll
      for (int off = 32; off > 0; off >>= 1) {
        ssq += __shfl_xor(ssq, off);
        ssk += __shfl_xor(ssk, off);
      }
      float qn = hv[0] * rsqrtf(ssq);
      float kn = hv[1] * rsqrtf(ssk);
      float ke = kn > 0.f ? kn : expm1f(kn);   // elu(unitnorm)
      kS[wave][l] = ke;
      qS[wave][l] = qn;                        // wave-local LDS: lockstep

      float vvl = hv[2];
      float* Arow = &Alds[wave][l * 65];       // stride 65: conflict-free
      float racc = 0.f;
#pragma unroll
      for (int q4 = 0; q4 < 16; ++q4) {
        float a0 = Arow[q4 * 4 + 0], a1 = Arow[q4 * 4 + 1];
        float a2 = Arow[q4 * 4 + 2], a3 = Arow[q4 * 4 + 3];
        float k0 = kS[wave][q4 * 4 + 0], k1 = kS[wave][q4 * 4 + 1];
        float k2 = kS[wave][q4 * 4 + 2], k3 = kS[wave][q4 * 4 + 3];
        float q0 = qS[wave][q4 * 4 + 0], q1 = qS[wave][q4 * 4 + 1];
        float q2 = qS[wave][q4 * 4 + 2], q3 = qS[wave][q4 * 4 + 3];
        a0 += k0 * vvl; a1 += k1 * vvl; a2 += k2 * vvl; a3 += k3 * vvl;
        racc += q0 * a0 + q1 * a1 + q2 * a2 + q3 * a3;
        Arow[q4 * 4 + 0] = a0; Arow[q4 * 4 + 1] = a1;
        Arow[q4 * 4 + 2] = a2; Arow[q4 * 4 + 3] = a3;
      }
      size_t ri = (size_t)b * DM + n * 64 + l;
      st16_llc(&Rbh[ri], bf(racc));

      if (t == SEQ - 1) {
        r32[ri] = racc;
        dout[65536  + pair * 64 + l] = ke;     // k output (f32)
        dout[131072 + pair * 64 + l] = qn;     // q output (f32)
      }
    }
    gsync(bar);
  }
}

// ---------------- final: out = r @ Wo.T + bo (f32) ----------------
__global__ __launch_bounds__(512) void out_gemm(const float* __restrict__ r32,
                                                const float* __restrict__ Wo,
                                                const float* __restrict__ bo,
                                                float* __restrict__ dout) {
  int b0 = blockIdx.x * 2;
  int o  = threadIdx.x;
  __shared__ float rL0[512];
  __shared__ float rL1[512];
  rL0[o] = r32[(size_t)b0 * DM + o];
  rL1[o] = r32[(size_t)(b0 + 1) * DM + o];
  __syncthreads();
  float a0 = bo[o], a1 = a0;
  const float* wrow = Wo + (size_t)o * DM;
  for (int c = 0; c < DM; ++c) {
    float w = wrow[c];
    a0 += rL0[c] * w;
    a1 += rL1[c] * w;
  }
  dout[(size_t)b0 * DM + o]       = a0;
  dout[(size_t)(b0 + 1) * DM + o] = a1;
}

extern "C" void kernel_launch(void* const* d_in, const int* in_sizes, int n_in,
                              void* d_out, int out_size, void* d_ws, size_t ws_size,
                              hipStream_t stream) {
  // Defensive input identification by element count (deterministic).
  int ix = 0, iwih = 1, iwhh = 2, ibih = 3, ibhh = 4, iwo = 5, ibo = 6;
  {
    int b1 = -1, b2 = -1;
    for (int i = 0; i < n_in; ++i) {
      int s = in_sizes[i];
      if      (s == SEQ * BSZ * DM) ix = i;
      else if (s == 4608 * 1024)    iwih = i;
      else if (s == 4608 * 1536)    iwhh = i;
      else if (s == DM * DM)        iwo = i;
      else if (s == DM)             ibo = i;
      else if (s == 4608)           { if (b1 < 0) b1 = i; else b2 = i; }
    }
    if (b1 >= 0) ibih = b1;
    if (b2 >= 0) ibhh = b2;
  }
  const float* x   = (const float*)d_in[ix];
  const float* Wih = (const float*)d_in[iwih];
  const float* Whh = (const float*)d_in[iwhh];
  const float* bih = (const float*)d_in[ibih];
  const float* bhh = (const float*)d_in[ibhh];
  const float* Wo  = (const float*)d_in[iwo];
  const float* bo  = (const float*)d_in[ibo];

  char* ws = (char*)d_ws;
  unsigned short* Wh  = (unsigned short*)(ws + OFF_WBH);
  float*          r32 = (float*)(ws + OFF_R32);
  unsigned*       bar = (unsigned*)(ws + OFF_BAR);
  float* dout = (float*)d_out;

  pk_wb  <<<11520, 256, 0, stream>>>(Wih, Whh, Wh, bar);
  pk_zero<<<256,   256, 0, stream>>>((f32x4*)(ws + OFF_RBH));
  fused  <<<NBLK,  256, 0, stream>>>(x, bih, bhh, ws, dout);
  out_gemm<<<64, 512, 0, stream>>>(r32, Wo, bo, dout);
}